// Round 3
// baseline (12564.356 us; speedup 1.0000x reference)
//
#include <hip/hip_runtime.h>
#include <cstdint>

#define DEV __device__ __forceinline__

DEV float sigmoidf_(float x) { return 1.0f / (1.0f + __expf(-x)); }
DEV float2 ld2(const float* p, int i) { return *(const float2*)(p + i); }
DEV void ld8(const float* p, int i, float* f) {
    float4 x = *(const float4*)(p + i);
    float4 y = *(const float4*)(p + i + 4);
    f[0]=x.x; f[1]=x.y; f[2]=x.z; f[3]=x.w; f[4]=y.x; f[5]=y.y; f[6]=y.z; f[7]=y.w;
}

// Problem constants
#define NB 32
#define NT 512
#define NAG 8
#define DS 16
#define DM 256
#define NH 8
#define NL 4
#define DR 64
#define AD 12
#define QKV_ROW 264                   // floats per agent row (256 + 8 pad), 16B-aligned
#define QKV_MAT (NAG * QKV_ROW)      // 2112 floats per matrix

enum { I_STATE=0, I_POS, I_VEL, I_TEAM, I_ALIVE, I_DEAD, I_EW1, I_EB1, I_EW2, I_EB2,
       I_TEMB, I_SEMB, I_TW1, I_TB1, I_TW2, I_TB2, I_ADW, I_ADB, I_NORMW,
       I_WQ, I_BQ, I_WK, I_BK, I_WV, I_BV, I_WO, I_BO, I_HW, I_HB, N_IN };

struct Args { const void* in[N_IN]; float* out; };

struct Smem {
    float sx[NAG][DM];            // residual x            8 KB
    float sstate[NAG][DS];        // masked state          512 B
    float sfeat[64][6];           // pair features         1.5 KB
    float sbias[NL][NH][64];      // attn bias, all layers 8 KB
    float ssc[NH][NAG][NAG];      // scores / probs        2 KB
    float snx[DM][8];             // k-major activations   8 KB
    float spos[NAG][2], svel[NAG][2], sinvr[NAG];
    int   steam[NAG], salive[NAG];
    __align__(16) char sbuf[2 * 64 * 65 * 4];   // 33280 B (trunk bufs / qkv alias)
};

__global__ __launch_bounds__(128) void yemong_kernel(Args a)
{
    __shared__ Smem S;
    const int t   = threadIdx.x;
    const int tok = blockIdx.x;
    const int c0  = 2 * t, c1 = 2 * t + 1;

    float (*sth)[65] = (float (*)[65])S.sbuf;
    float (*sto)[65] = (float (*)[65])(S.sbuf + 64 * 65 * 4);
    float* sqkv      = (float*)S.sbuf;   // 3 * QKV_MAT floats = 25344 B

    // alive-layout probe (byte bools vs int32 bools), wave-uniform
    unsigned m = 0;
    const unsigned* au = (const unsigned*)a.in[I_ALIVE];
    #pragma unroll
    for (int i = 0; i < 16; i++) m |= au[i];
    const bool abyte = (m > 1u);

    const float* g_pos   = (const float*)a.in[I_POS];
    const float* g_vel   = (const float*)a.in[I_VEL];
    const float* g_state = (const float*)a.in[I_STATE];
    const float* g_dead  = (const float*)a.in[I_DEAD];

    // ---------------- P0a: token metadata ----------------
    if (t < NAG) {
        S.steam[t] = ((const int*)a.in[I_TEAM])[tok * NAG + t];
        int v = abyte ? (int)((const unsigned char*)a.in[I_ALIVE])[tok * NAG + t]
                      : ((const int*)a.in[I_ALIVE])[tok * NAG + t];
        S.salive[t] = v ? 1 : 0;
    }
    if (t >= 64 && t < 64 + 16) {
        int idx = t - 64, n = idx >> 1, d = idx & 1;
        S.spos[n][d] = g_pos[(tok * NAG + n) * 2 + d] * 1024.0f;
        S.svel[n][d] = g_vel[(tok * NAG + n) * 2 + d];
    }
    __syncthreads();

    // ---------------- P0b: masked state + pair features ----------------
    {
        int n = t >> 4, kk = t & 15;
        S.sstate[n][kk] = S.salive[n] ? g_state[(tok * NAG + n) * DS + kk] : g_dead[kk];
    }
    if (t < 64) {
        int i = t >> 3, j = t & 7;
        float rx = S.spos[i][0] - S.spos[j][0];
        float ry = S.spos[i][1] - S.spos[j][1];
        rx -= rintf(rx * (1.0f / 1024.0f)) * 1024.0f;   // jnp.round = RNE
        ry -= rintf(ry * (1.0f / 1024.0f)) * 1024.0f;
        float vx = S.svel[i][0] - S.svel[j][0];
        float vy = S.svel[i][1] - S.svel[j][1];
        float dn = sqrtf(rx * rx + ry * ry + 1e-8f) * (1.0f / 1024.0f);
        S.sfeat[t][0] = rx * (1.0f / 1024.0f);
        S.sfeat[t][1] = ry * (1.0f / 1024.0f);
        S.sfeat[t][2] = vx;
        S.sfeat[t][3] = vy;
        S.sfeat[t][4] = dn;
        S.sfeat[t][5] = 1.0f / (1.0f + dn);
    }
    __syncthreads();

    // ---------------- P1: encoder layer 1 (16 -> 256) + silu ----------------
    {
        const float* W = (const float*)a.in[I_EW1];
        float a0[8] = {0}, a1[8] = {0};
        #pragma unroll
        for (int kk = 0; kk < DS; kk++) {
            float2 w = ld2(W, kk * DM + c0);
            #pragma unroll
            for (int n = 0; n < 8; n++) {
                float s = S.sstate[n][kk];
                a0[n] = fmaf(s, w.x, a0[n]);
                a1[n] = fmaf(s, w.y, a1[n]);
            }
        }
        float2 b = ld2((const float*)a.in[I_EB1], c0);
        #pragma unroll
        for (int n = 0; n < 8; n++) {
            float x0 = a0[n] + b.x, x1 = a1[n] + b.y;
            S.snx[c0][n] = x0 * sigmoidf_(x0);
            S.snx[c1][n] = x1 * sigmoidf_(x1);
        }
    }
    __syncthreads();

    // ---------------- P2: encoder layer 2 (256 -> 256) + embeddings ----------------
    {
        const float* W = (const float*)a.in[I_EW2];
        float a0[8] = {0}, a1[8] = {0};
        for (int kk = 0; kk < DM; kk++) {
            float v[8];
            ld8(&S.snx[0][0], kk * 8, v);
            float2 w = ld2(W, kk * DM + c0);
            #pragma unroll
            for (int n = 0; n < 8; n++) {
                a0[n] = fmaf(v[n], w.x, a0[n]);
                a1[n] = fmaf(v[n], w.y, a1[n]);
            }
        }
        float2 b = ld2((const float*)a.in[I_EB2], c0);
        #pragma unroll
        for (int n = 0; n < 8; n++) {
            float2 te = ld2((const float*)a.in[I_TEMB], S.steam[n] * DM + c0);
            float2 se = ld2((const float*)a.in[I_SEMB], n * DM + c0);
            S.sx[n][c0] = a0[n] + b.x + te.x + se.x;
            S.sx[n][c1] = a1[n] + b.y + te.y + se.y;
        }
    }
    __syncthreads();

    // ---------------- P3a: trunk layer 1 (6 -> 64) + silu ----------------
    {
        int p = t >> 1, rb = (t & 1) * 32;
        float f[6];
        #pragma unroll
        for (int q = 0; q < 6; q++) f[q] = S.sfeat[p][q];
        #pragma unroll
        for (int rr = 0; rr < 32; rr += 8) {
            float acc[8];
            ld8((const float*)a.in[I_TB1], rb + rr, acc);
            #pragma unroll
            for (int kk = 0; kk < 6; kk++) {
                float w[8];
                ld8((const float*)a.in[I_TW1], kk * DR + rb + rr, w);
                #pragma unroll
                for (int e = 0; e < 8; e++) acc[e] = fmaf(f[kk], w[e], acc[e]);
            }
            #pragma unroll
            for (int e = 0; e < 8; e++) {
                float v = acc[e];
                sth[p][rb + rr + e] = v * sigmoidf_(v);
            }
        }
    }
    __syncthreads();

    // ---------------- P3b: trunk layer 2 (64 -> 64) ----------------
    {
        int p = t >> 1, rb = (t & 1) * 32;
        float acc[32];
        #pragma unroll
        for (int g = 0; g < 4; g++) ld8((const float*)a.in[I_TB2], rb + g * 8, &acc[g * 8]);
        for (int kk = 0; kk < DR; kk++) {
            float th = sth[p][kk];
            #pragma unroll
            for (int g = 0; g < 4; g++) {
                float w[8];
                ld8((const float*)a.in[I_TW2], kk * DR + rb + g * 8, w);
                #pragma unroll
                for (int e = 0; e < 8; e++) acc[g * 8 + e] = fmaf(th, w[e], acc[g * 8 + e]);
            }
        }
        #pragma unroll
        for (int rr = 0; rr < 32; rr++) sto[p][rb + rr] = acc[rr];
    }
    __syncthreads();

    // ---------------- P3c: attention bias, all 4 layers ----------------
    {
        int p = t & 63, l2 = t >> 6;
        #pragma unroll
        for (int li = 0; li < 2; li++) {
            int l = l2 * 2 + li;
            float acc[8];
            ld8((const float*)a.in[I_ADB], l * NH, acc);
            for (int r = 0; r < DR; r++) {
                float to = sto[p][r];
                float w[8];
                ld8((const float*)a.in[I_ADW], (l * DR + r) * NH, w);
                #pragma unroll
                for (int h = 0; h < 8; h++) acc[h] = fmaf(to, w[h], acc[h]);
            }
            #pragma unroll
            for (int h = 0; h < 8; h++) S.sbias[l][h][p] = acc[h];
        }
    }
    __syncthreads();
    // NOTE: from here on, sth/sto are dead; sqkv aliases their storage.

    // ---------------- Layers ----------------
    for (int l = 0; l < NL; l++) {
        // P4a: RMS statistics (16 lanes per agent)
        {
            int n = t >> 4, l16 = t & 15;
            float p = 0.0f;
            #pragma unroll
            for (int j = 0; j < 16; j++) {
                float v = S.sx[n][l16 + 16 * j];
                p = fmaf(v, v, p);
            }
            p += __shfl_xor(p, 8, 16);
            p += __shfl_xor(p, 4, 16);
            p += __shfl_xor(p, 2, 16);
            p += __shfl_xor(p, 1, 16);
            if (l16 == 0) S.sinvr[n] = rsqrtf(p * (1.0f / 256.0f) + 1e-6f);
        }
        __syncthreads();

        // P4b: nx = x * invr * norm_w  (k-major)
        {
            float2 w = ld2((const float*)a.in[I_NORMW], l * DM + c0);
            #pragma unroll
            for (int n = 0; n < 8; n++) {
                float ir = S.sinvr[n];
                S.snx[c0][n] = S.sx[n][c0] * ir * w.x;
                S.snx[c1][n] = S.sx[n][c1] * ir * w.y;
            }
        }
        __syncthreads();

        // P4c: Q, K, V projections
        {
            const void* Wm[3] = {a.in[I_WQ], a.in[I_WK], a.in[I_WV]};
            const void* bm[3] = {a.in[I_BQ], a.in[I_BK], a.in[I_BV]};
            for (int mm = 0; mm < 3; mm++) {
                const float* W = (const float*)Wm[mm] + l * DM * DM;
                float a0[8] = {0}, a1[8] = {0};
                for (int kk = 0; kk < DM; kk++) {
                    float v[8];
                    ld8(&S.snx[0][0], kk * 8, v);
                    float2 w = ld2(W, kk * DM + c0);
                    #pragma unroll
                    for (int n = 0; n < 8; n++) {
                        a0[n] = fmaf(v[n], w.x, a0[n]);
                        a1[n] = fmaf(v[n], w.y, a1[n]);
                    }
                }
                float2 b = ld2((const float*)bm[mm], l * DM + c0);
                #pragma unroll
                for (int n = 0; n < 8; n++) {
                    float2 r; r.x = a0[n] + b.x; r.y = a1[n] + b.y;
                    *(float2*)&sqkv[mm * QKV_MAT + n * QKV_ROW + c0] = r;
                }
            }
        }
        __syncthreads();

        // P4d: scores  sc[h][i][j] = scale*q_i.k_j + bias, masked
        {
            #pragma unroll
            for (int it = 0; it < 4; it++) {
                int e = t + 128 * it;
                int h = e >> 6, i = (e >> 3) & 7, j = e & 7;
                const float* q = &sqkv[0 * QKV_MAT + i * QKV_ROW + h * 32];
                const float* k = &sqkv[1 * QKV_MAT + j * QKV_ROW + h * 32];
                float dot = 0.0f;
                #pragma unroll
                for (int g = 0; g < 4; g++) {
                    float qf[8], kf[8];
                    ld8(q, g * 8, qf);
                    ld8(k, g * 8, kf);
                    #pragma unroll
                    for (int e2 = 0; e2 < 8; e2++) dot = fmaf(qf[e2], kf[e2], dot);
                }
                float v = dot * 0.17677669529663689f + S.sbias[l][h][i * 8 + j];
                if (!S.salive[j]) v = -1000000000.0f;
                S.ssc[h][i][j] = v;
            }
        }
        __syncthreads();

        // P4e: softmax over j
        if (t < 64) {
            int h = t >> 3, i = t & 7;
            float* row = S.ssc[h][i];
            float mx = row[0];
            #pragma unroll
            for (int j = 1; j < 8; j++) mx = fmaxf(mx, row[j]);
            float ex[8], s = 0.0f;
            #pragma unroll
            for (int j = 0; j < 8; j++) { ex[j] = __expf(row[j] - mx); s += ex[j]; }
            float inv = 1.0f / s;
            #pragma unroll
            for (int j = 0; j < 8; j++) row[j] = ex[j] * inv;
        }
        __syncthreads();

        // P4f: o = a @ v   (k-major into snx)
        {
            int h = t >> 4;
            float a0[8] = {0}, a1[8] = {0};
            #pragma unroll
            for (int j = 0; j < 8; j++) {
                float2 v = *(const float2*)&sqkv[2 * QKV_MAT + j * QKV_ROW + c0];
                #pragma unroll
                for (int n = 0; n < 8; n++) {
                    float av = S.ssc[h][n][j];
                    a0[n] = fmaf(av, v.x, a0[n]);
                    a1[n] = fmaf(av, v.y, a1[n]);
                }
            }
            #pragma unroll
            for (int n = 0; n < 8; n++) {
                S.snx[c0][n] = a0[n];
                S.snx[c1][n] = a1[n];
            }
        }
        __syncthreads();

        // P4g: x += o @ Wo + bo
        {
            const float* W = (const float*)a.in[I_WO] + l * DM * DM;
            float a0[8] = {0}, a1[8] = {0};
            for (int kk = 0; kk < DM; kk++) {
                float v[8];
                ld8(&S.snx[0][0], kk * 8, v);
                float2 w = ld2(W, kk * DM + c0);
                #pragma unroll
                for (int n = 0; n < 8; n++) {
                    a0[n] = fmaf(v[n], w.x, a0[n]);
                    a1[n] = fmaf(v[n], w.y, a1[n]);
                }
            }
            float2 b = ld2((const float*)a.in[I_BO], l * DM + c0);
            #pragma unroll
            for (int n = 0; n < 8; n++) {
                S.sx[n][c0] += a0[n] + b.x;
                S.sx[n][c1] += a1[n] + b.y;
            }
        }
        __syncthreads();
    }

    // ---------------- P5: head (256 -> 12) ----------------
    if (t < NAG * AD) {
        int n = t / AD, ad = t % AD;
        const float* HW = (const float*)a.in[I_HW];
        float acc = ((const float*)a.in[I_HB])[ad];
        for (int kk = 0; kk < DM; kk += 4) {
            float4 xv = *(const float4*)&S.sx[n][kk];
            acc = fmaf(xv.x, HW[(kk + 0) * AD + ad], acc);
            acc = fmaf(xv.y, HW[(kk + 1) * AD + ad], acc);
            acc = fmaf(xv.z, HW[(kk + 2) * AD + ad], acc);
            acc = fmaf(xv.w, HW[(kk + 3) * AD + ad], acc);
        }
        a.out[(tok * NAG + n) * AD + ad] = acc;
    }
}

extern "C" void kernel_launch(void* const* d_in, const int* in_sizes, int n_in,
                              void* d_out, int out_size, void* d_ws, size_t ws_size,
                              hipStream_t stream) {
    (void)in_sizes; (void)n_in; (void)ws_size; (void)d_ws; (void)out_size;
    Args a;
    for (int i = 0; i < N_IN; i++) a.in[i] = d_in[i];
    a.out = (float*)d_out;
    dim3 grid(NB * NT), block(128);
    hipLaunchKernelGGL(yemong_kernel, grid, block, 0, stream, a);
}

// Round 4
// 1681.475 us; speedup vs baseline: 7.4722x; 7.4722x over previous
//
#include <hip/hip_runtime.h>
#include <cstdint>

#define DEV __device__ __forceinline__

typedef __attribute__((ext_vector_type(8))) short short8;
typedef __attribute__((ext_vector_type(4))) float floatx4;

DEV unsigned short f2bf(float f) {
    unsigned u = __float_as_uint(f);
    return (unsigned short)((u + 0x7fffu + ((u >> 16) & 1u)) >> 16);  // RNE
}
DEV void unpack2(unsigned u, float& a, float& b) {
    a = __uint_as_float(u << 16);
    b = __uint_as_float(u & 0xffff0000u);
}
DEV unsigned pack2f(float a, float b) { return (unsigned)f2bf(a) | ((unsigned)f2bf(b) << 16); }
DEV float sigm(float x) { return 1.0f / (1.0f + __expf(-x)); }

// Problem constants
#define NAG 8
#define DM 256
#define NH 8
#define NL 4
#define AD 12
#define TPB 4                 // tokens per block
#define MROWS 32              // TPB*NAG
#define NBLK 4096             // 16384 tokens / TPB

// ws (bf16 units) offsets: weights in MFMA B-frag order [ks][n][quad][j]
#define OFF_E1   0            // encW1, K=16 zero-padded to 32 (1 ks-block of 8192)
#define OFF_E2   8192         // encW2 (8 ks-blocks)
#define OFF_QKVO 73728        // 16 matrices of 65536: (l*4+m), m: 0=q 1=k 2=v 3=o
#define OFF_TW2  1122304      // trunk W2 64x64 (2 ks-blocks of 2048)
#define OFF_ADW  1126400      // adapt_W concat (64 x 32), n = l*8+h (2 ks-blocks of 1024)
#define WS_TOTAL 1128448      // ushorts
#define WS_BYTES (WS_TOTAL * 2)

// dynamic LDS layout (bytes)
#define L_A      0            // 36864: trunk: sth[256][72] | layers: sq[32][264] @0, sk @18432
#define L_B      36864        // 36864: trunk: sto[256][72] | layers: snx[32][264] @0, sv @18432
#define L_SX     73728        // 33792: sx fp32 [32][264]
#define L_SBIAS  107520       // 32768: fp32 [tok4][l4][h8][pair64]
#define L_SP     140288       // 8192:  fp32 [tok4*h8][i8][j8] probs
#define L_SPOS   148480       // 256
#define L_SVEL   148736       // 256
#define L_ALIVE  148992       // 128
#define L_TEAM   149120       // 128
#define SMEM_BYTES 149248

enum { I_STATE=0, I_POS, I_VEL, I_TEAM, I_ALIVE, I_DEAD, I_EW1, I_EB1, I_EW2, I_EB2,
       I_TEMB, I_SEMB, I_TW1, I_TB1, I_TW2, I_TB2, I_ADW, I_ADB, I_NORMW,
       I_WQ, I_BQ, I_WK, I_BK, I_WV, I_BV, I_WO, I_BO, I_HW, I_HB, N_IN };

struct Args { const void* in[N_IN]; float* out; };

// ---------------- weight pre-conversion: fp32 [K][N] -> bf16 frag order ----------------
__global__ __launch_bounds__(256) void prep_kernel(Args a, unsigned short* ws)
{
    int e = blockIdx.x * 256 + threadIdx.x;
    int mat = blockIdx.y;
    int size, offs, N, Kreal;
    const float* src;
    if (mat == 0)      { size = 8192;  offs = OFF_E1;  N = 256; Kreal = 16;  src = (const float*)a.in[I_EW1]; }
    else if (mat == 1) { size = 65536; offs = OFF_E2;  N = 256; Kreal = 256; src = (const float*)a.in[I_EW2]; }
    else if (mat < 18) {
        int q = mat - 2, l = q >> 2, m = q & 3;
        int wi = (m == 0) ? I_WQ : (m == 1) ? I_WK : (m == 2) ? I_WV : I_WO;
        size = 65536; offs = OFF_QKVO + q * 65536; N = 256; Kreal = 256;
        src = (const float*)a.in[wi] + l * 65536;
    }
    else if (mat == 18) { size = 4096; offs = OFF_TW2; N = 64; Kreal = 64; src = (const float*)a.in[I_TW2]; }
    else                { size = 2048; offs = OFF_ADW; N = 32; Kreal = 64; src = (const float*)a.in[I_ADW]; }
    if (e >= size) return;
    int ksblk = N * 32;
    int ks = e / ksblk, rem = e % ksblk;
    int n = rem >> 5, quad = (rem >> 3) & 3, j = rem & 7;
    int k = ks * 32 + quad * 8 + j;
    float v = 0.0f;
    if (k < Kreal) {
        if (mat == 19) v = src[((n >> 3) * 64 + k) * 8 + (n & 7)];   // adapt_W[l][k][h], n=l*8+h
        else           v = src[k * N + n];
    }
    ws[offs + e] = f2bf(v);
}

// ---------------- MFMA fragment loaders ----------------
DEV short8 ld_u4(const unsigned short* p) {
    union { uint4 u; short8 s; } c;
    c.u = *(const uint4*)p;
    return c.s;
}
// A: LDS bf16 [row][k], lane holds A[row0+(lane&15)][ks*32 + quad*8 + j]
DEV short8 ld_afrag(const unsigned short* A, int stride, int row0, int kofs, int l15, int quad) {
    return ld_u4(A + (row0 + l15) * stride + kofs + quad * 8);
}
// B from ws frag order: one dwordx4
DEV short8 ld_bws(const unsigned short* w, int ksblk, int ks, int col, int l15, int quad) {
    return ld_u4(w + ks * ksblk + (col + l15) * 32 + quad * 8);
}
// B fallback: strided fp32 [K][N]
DEV short8 ld_bf32(const float* W, int N, int Kreal, int ks, int col, int l15, int quad) {
    short8 r;
    #pragma unroll
    for (int j = 0; j < 8; j++) {
        int k = ks * 32 + quad * 8 + j;
        float v = (k < Kreal) ? W[k * N + col + l15] : 0.0f;
        r[j] = (short)f2bf(v);
    }
    return r;
}

// M=32, N=256 (wave handles cols 64*wv..+63), K = Kb*32, A stride 264
template<bool UW>
DEV void gemm32(const unsigned short* A, const unsigned short* wsW, const float* Wf,
                int Kb, int Kreal, int colw, int l15, int quad, floatx4 acc[2][4]) {
    for (int ks = 0; ks < Kb; ks++) {
        short8 af0 = ld_afrag(A, 264, 0,  ks * 32, l15, quad);
        short8 af1 = ld_afrag(A, 264, 16, ks * 32, l15, quad);
        short8 bf[4];
        #pragma unroll
        for (int nj = 0; nj < 4; nj++)
            bf[nj] = UW ? ld_bws(wsW, 8192, ks, colw + nj * 16, l15, quad)
                        : ld_bf32(Wf, 256, Kreal, ks, colw + nj * 16, l15, quad);
        #pragma unroll
        for (int nj = 0; nj < 4; nj++) {
            acc[0][nj] = __builtin_amdgcn_mfma_f32_16x16x32_bf16(af0, bf[nj], acc[0][nj], 0, 0, 0);
            acc[1][nj] = __builtin_amdgcn_mfma_f32_16x16x32_bf16(af1, bf[nj], acc[1][nj], 0, 0, 0);
        }
    }
}

template<bool UW>
__global__ __launch_bounds__(256) void yemong_mfma(Args a, const unsigned short* ws)
{
    extern __shared__ char smem[];
    unsigned short* sth = (unsigned short*)(smem + L_A);          // [256][72]
    unsigned short* sq  = (unsigned short*)(smem + L_A);          // [32][264]
    unsigned short* sk  = (unsigned short*)(smem + L_A + 18432);
    unsigned short* sto = (unsigned short*)(smem + L_B);          // [256][72]
    unsigned short* snx = (unsigned short*)(smem + L_B);          // [32][264]
    unsigned short* sv  = (unsigned short*)(smem + L_B + 18432);
    float* sx    = (float*)(smem + L_SX);                         // [32][264]
    float* sbias = (float*)(smem + L_SBIAS);
    float* sP    = (float*)(smem + L_SP);
    float* spos  = (float*)(smem + L_SPOS);
    float* svel  = (float*)(smem + L_SVEL);
    int*   salive= (int*)(smem + L_ALIVE);
    int*   steam = (int*)(smem + L_TEAM);

    const int t = threadIdx.x;
    const int bid = blockIdx.x;
    const int lane = t & 63, wv = t >> 6;
    const int l15 = lane & 15, quad = lane >> 4;

    // alive-layout probe (byte bools vs int32 bools), uniform
    unsigned mp = 0;
    const unsigned* au = (const unsigned*)a.in[I_ALIVE];
    #pragma unroll
    for (int i = 0; i < 16; i++) mp |= au[i];
    const bool abyte = (mp > 1u);
    auto aliveAt = [&](int r) -> int {
        int gi = bid * MROWS + r;
        return abyte ? (int)((const unsigned char*)a.in[I_ALIVE])[gi]
                     : ((const int*)a.in[I_ALIVE])[gi];
    };

    // -------- P0: metadata + masked state staging (bf16, k zero-padded to 32) --------
    if (t < MROWS) {
        salive[t] = aliveAt(t) ? 1 : 0;
        steam[t]  = ((const int*)a.in[I_TEAM])[bid * MROWS + t];
    }
    if (t >= 64 && t < 128) {
        int idx = t - 64, n = idx >> 1, d = idx & 1;
        spos[n * 2 + d] = ((const float*)a.in[I_POS])[(bid * MROWS + n) * 2 + d] * 1024.0f;
        svel[n * 2 + d] = ((const float*)a.in[I_VEL])[(bid * MROWS + n) * 2 + d];
    }
    {
        const float* gs = (const float*)a.in[I_STATE];
        const float* gd = (const float*)a.in[I_DEAD];
        #pragma unroll
        for (int it = 0; it < 4; it++) {
            int idx = t + 256 * it;              // 32 rows x 32 k
            int r = idx >> 5, kk = idx & 31;
            float v = 0.0f;
            if (kk < 16) v = aliveAt(r) ? gs[(bid * MROWS + r) * 16 + kk] : gd[kk];
            snx[r * 264 + kk] = f2bf(v);
        }
    }
    __syncthreads();

    // -------- P1: enc1 (16->256) + silu, in place over snx --------
    {
        floatx4 acc[2][4] = {};
        gemm32<UW>(snx, ws + OFF_E1, (const float*)a.in[I_EW1], 1, 16, wv * 64, l15, quad, acc);
        __syncthreads();                          // all A reads done before overwriting snx
        const float* b1 = (const float*)a.in[I_EB1];
        #pragma unroll
        for (int nj = 0; nj < 4; nj++) {
            int c = wv * 64 + nj * 16 + l15;
            float bb = b1[c];
            #pragma unroll
            for (int mi = 0; mi < 2; mi++)
                #pragma unroll
                for (int r = 0; r < 4; r++) {
                    int row = mi * 16 + quad * 4 + r;
                    float v = acc[mi][nj][r] + bb;
                    snx[row * 264 + c] = f2bf(v * sigm(v));
                }
        }
    }
    __syncthreads();

    // -------- P2: enc2 (256->256) + b2 + team/ship emb -> sx fp32 --------
    {
        floatx4 acc[2][4] = {};
        gemm32<UW>(snx, ws + OFF_E2, (const float*)a.in[I_EW2], 8, 256, wv * 64, l15, quad, acc);
        const float* b2 = (const float*)a.in[I_EB2];
        const float* te = (const float*)a.in[I_TEMB];
        const float* se = (const float*)a.in[I_SEMB];
        #pragma unroll
        for (int nj = 0; nj < 4; nj++) {
            int c = wv * 64 + nj * 16 + l15;
            float bb = b2[c];
            #pragma unroll
            for (int mi = 0; mi < 2; mi++)
                #pragma unroll
                for (int r = 0; r < 4; r++) {
                    int row = mi * 16 + quad * 4 + r;
                    sx[row * 264 + c] = acc[mi][nj][r] + bb + te[steam[row] * 256 + c] + se[(row & 7) * 256 + c];
                }
        }
    }
    __syncthreads();

    // -------- P3a: pair features + trunk1 (6->64) + silu -> sth (one pair/thread) --------
    {
        int tok_l = t >> 6, i = (t >> 3) & 7, j = t & 7;
        int ri = tok_l * 8 + i, rj = tok_l * 8 + j;
        float rx = spos[ri * 2 + 0] - spos[rj * 2 + 0];
        float ry = spos[ri * 2 + 1] - spos[rj * 2 + 1];
        rx -= rintf(rx * (1.0f / 1024.0f)) * 1024.0f;
        ry -= rintf(ry * (1.0f / 1024.0f)) * 1024.0f;
        float vx = svel[ri * 2 + 0] - svel[rj * 2 + 0];
        float vy = svel[ri * 2 + 1] - svel[rj * 2 + 1];
        float dn = sqrtf(rx * rx + ry * ry + 1e-8f) * (1.0f / 1024.0f);
        float f0 = rx * (1.0f / 1024.0f), f1 = ry * (1.0f / 1024.0f);
        float f4 = dn, f5 = 1.0f / (1.0f + dn);
        const float* W1 = (const float*)a.in[I_TW1];
        const float* B1 = (const float*)a.in[I_TB1];
        #pragma unroll
        for (int r = 0; r < 64; r += 2) {
            float v0 = B1[r], v1 = B1[r + 1];
            v0 = fmaf(f0, W1[r],       v0); v1 = fmaf(f0, W1[r + 1],       v1);
            v0 = fmaf(f1, W1[64 + r],  v0); v1 = fmaf(f1, W1[64 + r + 1],  v1);
            v0 = fmaf(vx, W1[128 + r], v0); v1 = fmaf(vx, W1[128 + r + 1], v1);
            v0 = fmaf(vy, W1[192 + r], v0); v1 = fmaf(vy, W1[192 + r + 1], v1);
            v0 = fmaf(f4, W1[256 + r], v0); v1 = fmaf(f4, W1[256 + r + 1], v1);
            v0 = fmaf(f5, W1[320 + r], v0); v1 = fmaf(f5, W1[320 + r + 1], v1);
            *(unsigned*)&sth[t * 72 + r] = pack2f(v0 * sigm(v0), v1 * sigm(v1));
        }
    }
    __syncthreads();

    // -------- P3b: trunk2 (64->64) MFMA, M=256 -> sto --------
    {
        floatx4 acc[4][4] = {};
        for (int ks = 0; ks < 2; ks++) {
            short8 af[4], bf[4];
            #pragma unroll
            for (int mi = 0; mi < 4; mi++)
                af[mi] = ld_afrag(sth, 72, wv * 64 + mi * 16, ks * 32, l15, quad);
            #pragma unroll
            for (int nj = 0; nj < 4; nj++)
                bf[nj] = UW ? ld_bws(ws + OFF_TW2, 2048, ks, nj * 16, l15, quad)
                            : ld_bf32((const float*)a.in[I_TW2], 64, 64, ks, nj * 16, l15, quad);
            #pragma unroll
            for (int mi = 0; mi < 4; mi++)
                #pragma unroll
                for (int nj = 0; nj < 4; nj++)
                    acc[mi][nj] = __builtin_amdgcn_mfma_f32_16x16x32_bf16(af[mi], bf[nj], acc[mi][nj], 0, 0, 0);
        }
        const float* B2 = (const float*)a.in[I_TB2];
        #pragma unroll
        for (int nj = 0; nj < 4; nj++) {
            int c = nj * 16 + l15;
            float bb = B2[c];
            #pragma unroll
            for (int mi = 0; mi < 4; mi++)
                #pragma unroll
                for (int r = 0; r < 4; r++) {
                    int row = wv * 64 + mi * 16 + quad * 4 + r;
                    sto[row * 72 + c] = f2bf(acc[mi][nj][r] + bb);
                }
        }
    }
    __syncthreads();

    // -------- P3c: adapt bias GEMM (64->32 = 4 layers x 8 heads) -> sbias --------
    {
        floatx4 acc[4][2] = {};
        for (int ks = 0; ks < 2; ks++) {
            short8 af[4], bf[2];
            #pragma unroll
            for (int mi = 0; mi < 4; mi++)
                af[mi] = ld_afrag(sto, 72, wv * 64 + mi * 16, ks * 32, l15, quad);
            #pragma unroll
            for (int nj = 0; nj < 2; nj++) {
                if (UW) bf[nj] = ld_bws(ws + OFF_ADW, 1024, ks, nj * 16, l15, quad);
                else {
                    const float* adw = (const float*)a.in[I_ADW];
                    int n = nj * 16 + l15;
                    #pragma unroll
                    for (int j = 0; j < 8; j++) {
                        int k = ks * 32 + quad * 8 + j;
                        bf[nj][j] = (short)f2bf(k < 64 ? adw[((n >> 3) * 64 + k) * 8 + (n & 7)] : 0.0f);
                    }
                }
            }
            #pragma unroll
            for (int mi = 0; mi < 4; mi++)
                #pragma unroll
                for (int nj = 0; nj < 2; nj++)
                    acc[mi][nj] = __builtin_amdgcn_mfma_f32_16x16x32_bf16(af[mi], bf[nj], acc[mi][nj], 0, 0, 0);
        }
        const float* adb = (const float*)a.in[I_ADB];
        #pragma unroll
        for (int nj = 0; nj < 2; nj++) {
            int n = nj * 16 + l15;
            int ll = n >> 3, h = n & 7;
            float bb = adb[ll * 8 + h];
            #pragma unroll
            for (int mi = 0; mi < 4; mi++)
                #pragma unroll
                for (int r = 0; r < 4; r++) {
                    int row = wv * 64 + mi * 16 + quad * 4 + r;
                    int tok_l = row >> 6, pair = row & 63;
                    sbias[((tok_l * 4 + ll) * 8 + h) * 64 + pair] = acc[mi][nj][r] + bb;
                }
        }
    }
    __syncthreads();

    // -------- P4: layers --------
    for (int l = 0; l < NL; l++) {
        // rms + nx -> snx (bf16)
        {
            int row = t >> 3, p = t & 7;
            float xv[32], ss = 0.0f;
            #pragma unroll
            for (int cc = 0; cc < 32; cc++) { xv[cc] = sx[row * 264 + p * 32 + cc]; ss = fmaf(xv[cc], xv[cc], ss); }
            ss += __shfl_xor(ss, 1); ss += __shfl_xor(ss, 2); ss += __shfl_xor(ss, 4);
            float invr = rsqrtf(ss * (1.0f / 256.0f) + 1e-6f);
            const float* nw = (const float*)a.in[I_NORMW] + l * 256 + p * 32;
            #pragma unroll
            for (int cc = 0; cc < 32; cc += 2)
                *(unsigned*)&snx[row * 264 + p * 32 + cc] = pack2f(xv[cc] * invr * nw[cc], xv[cc + 1] * invr * nw[cc + 1]);
        }
        __syncthreads();

        // Q, K, V projections
        {
            floatx4 acc[2][4];
            auto store = [&](floatx4 (&ac)[2][4], const float* bias, unsigned short* dst) {
                #pragma unroll
                for (int nj = 0; nj < 4; nj++) {
                    int c = wv * 64 + nj * 16 + l15;
                    float bb = bias[c];
                    #pragma unroll
                    for (int mi = 0; mi < 2; mi++)
                        #pragma unroll
                        for (int r = 0; r < 4; r++) {
                            int row = mi * 16 + quad * 4 + r;
                            dst[row * 264 + c] = f2bf(ac[mi][nj][r] + bb);
                        }
                }
            };
            #pragma unroll
            for (int mi = 0; mi < 2; mi++) for (int nj = 0; nj < 4; nj++) acc[mi][nj] = floatx4{0,0,0,0};
            gemm32<UW>(snx, ws + OFF_QKVO + (l * 4 + 0) * 65536, (const float*)a.in[I_WQ] + l * 65536, 8, 256, wv * 64, l15, quad, acc);
            store(acc, (const float*)a.in[I_BQ] + l * 256, sq);
            #pragma unroll
            for (int mi = 0; mi < 2; mi++) for (int nj = 0; nj < 4; nj++) acc[mi][nj] = floatx4{0,0,0,0};
            gemm32<UW>(snx, ws + OFF_QKVO + (l * 4 + 1) * 65536, (const float*)a.in[I_WK] + l * 65536, 8, 256, wv * 64, l15, quad, acc);
            store(acc, (const float*)a.in[I_BK] + l * 256, sk);
            #pragma unroll
            for (int mi = 0; mi < 2; mi++) for (int nj = 0; nj < 4; nj++) acc[mi][nj] = floatx4{0,0,0,0};
            gemm32<UW>(snx, ws + OFF_QKVO + (l * 4 + 2) * 65536, (const float*)a.in[I_WV] + l * 65536, 8, 256, wv * 64, l15, quad, acc);
            store(acc, (const float*)a.in[I_BV] + l * 256, sv);
        }
        __syncthreads();

        // scores + softmax -> sP   (thread = (tok, head, i-row))
        {
            int tok_l = t >> 6, h = (t >> 3) & 7, i = t & 7;
            int rq = tok_l * 8 + i;
            float qv[32];
            #pragma unroll
            for (int d = 0; d < 32; d += 2) unpack2(*(const unsigned*)&sq[rq * 264 + h * 32 + d], qv[d], qv[d + 1]);
            float sc[8];
            #pragma unroll
            for (int j = 0; j < 8; j++) {
                int rk = tok_l * 8 + j;
                float dot = 0.0f;
                #pragma unroll
                for (int d = 0; d < 32; d += 2) {
                    float k0, k1;
                    unpack2(*(const unsigned*)&sk[rk * 264 + h * 32 + d], k0, k1);
                    dot = fmaf(qv[d], k0, fmaf(qv[d + 1], k1, dot));
                }
                float b = sbias[((tok_l * 4 + l) * 8 + h) * 64 + i * 8 + j];
                sc[j] = salive[tok_l * 8 + j] ? fmaf(dot, 0.17677669529663689f, b) : -1000000000.0f;
            }
            float mx = sc[0];
            #pragma unroll
            for (int j = 1; j < 8; j++) mx = fmaxf(mx, sc[j]);
            float ex[8], s = 0.0f;
            #pragma unroll
            for (int j = 0; j < 8; j++) { ex[j] = __expf(sc[j] - mx); s += ex[j]; }
            float inv = 1.0f / s;
            #pragma unroll
            for (int j = 0; j < 8; j++) sP[((tok_l * 8 + h) * 8 + i) * 8 + j] = ex[j] * inv;
        }
        __syncthreads();

        // o = P @ v -> snx (bf16; nx dead)
        {
            int h = t >> 5, r = t & 31;
            int tok_l = r >> 3, i = r & 7;
            float acc2[32];
            #pragma unroll
            for (int cc = 0; cc < 32; cc++) acc2[cc] = 0.0f;
            #pragma unroll
            for (int j = 0; j < 8; j++) {
                float p = sP[((tok_l * 8 + h) * 8 + i) * 8 + j];
                int rv = tok_l * 8 + j;
                #pragma unroll
                for (int cc = 0; cc < 32; cc += 2) {
                    float v0, v1;
                    unpack2(*(const unsigned*)&sv[rv * 264 + h * 32 + cc], v0, v1);
                    acc2[cc] = fmaf(p, v0, acc2[cc]);
                    acc2[cc + 1] = fmaf(p, v1, acc2[cc + 1]);
                }
            }
            #pragma unroll
            for (int cc = 0; cc < 32; cc += 2)
                *(unsigned*)&snx[r * 264 + h * 32 + cc] = pack2f(acc2[cc], acc2[cc + 1]);
        }
        __syncthreads();

        // x += o @ Wo + bo
        {
            floatx4 acc[2][4] = {};
            gemm32<UW>(snx, ws + OFF_QKVO + (l * 4 + 3) * 65536, (const float*)a.in[I_WO] + l * 65536, 8, 256, wv * 64, l15, quad, acc);
            const float* bo = (const float*)a.in[I_BO] + l * 256;
            #pragma unroll
            for (int nj = 0; nj < 4; nj++) {
                int c = wv * 64 + nj * 16 + l15;
                float bb = bo[c];
                #pragma unroll
                for (int mi = 0; mi < 2; mi++)
                    #pragma unroll
                    for (int r = 0; r < 4; r++) {
                        int row = mi * 16 + quad * 4 + r;
                        sx[row * 264 + c] += acc[mi][nj][r] + bb;
                    }
            }
        }
        __syncthreads();
    }

    // -------- P5: head (256 -> 12), 8 threads/row k-split + shuffle reduce --------
    {
        int row = t >> 3, p = t & 7;
        const float* HW = (const float*)a.in[I_HW];
        float ah[12];
        #pragma unroll
        for (int c = 0; c < 12; c++) ah[c] = 0.0f;
        for (int kk = p * 32; kk < p * 32 + 32; kk++) {
            float xv = sx[row * 264 + kk];
            #pragma unroll
            for (int c = 0; c < 12; c++) ah[c] = fmaf(xv, HW[kk * 12 + c], ah[c]);
        }
        #pragma unroll
        for (int c = 0; c < 12; c++) {
            ah[c] += __shfl_xor(ah[c], 1);
            ah[c] += __shfl_xor(ah[c], 2);
            ah[c] += __shfl_xor(ah[c], 4);
        }
        if (p == 0) {
            const float* hb = (const float*)a.in[I_HB];
            #pragma unroll
            for (int c = 0; c < 12; c++)
                a.out[(bid * MROWS + row) * AD + c] = ah[c] + hb[c];
        }
    }
}

extern "C" void kernel_launch(void* const* d_in, const int* in_sizes, int n_in,
                              void* d_out, int out_size, void* d_ws, size_t ws_size,
                              hipStream_t stream) {
    (void)in_sizes; (void)n_in; (void)out_size;
    Args a;
    for (int i = 0; i < N_IN; i++) a.in[i] = d_in[i];
    a.out = (float*)d_out;
    unsigned short* ws16 = (unsigned short*)d_ws;
    const bool use_ws = (ws_size >= (size_t)WS_BYTES) && (d_ws != nullptr);
    if (use_ws) {
        hipLaunchKernelGGL(prep_kernel, dim3(256, 20), dim3(256), 0, stream, a, ws16);
        hipFuncSetAttribute((const void*)yemong_mfma<true>, hipFuncAttributeMaxDynamicSharedMemorySize, SMEM_BYTES);
        hipLaunchKernelGGL((yemong_mfma<true>), dim3(NBLK), dim3(256), SMEM_BYTES, stream, a, ws16);
    } else {
        hipFuncSetAttribute((const void*)yemong_mfma<false>, hipFuncAttributeMaxDynamicSharedMemorySize, SMEM_BYTES);
        hipLaunchKernelGGL((yemong_mfma<false>), dim3(NBLK), dim3(256), SMEM_BYTES, stream, a, ws16);
    }
}

// Round 5
// 1093.279 us; speedup vs baseline: 11.4924x; 1.5380x over previous
//
#include <hip/hip_runtime.h>
#include <cstdint>

#define DEV __device__ __forceinline__

typedef __attribute__((ext_vector_type(8))) short short8;
typedef __attribute__((ext_vector_type(4))) float floatx4;
typedef unsigned short u16;

DEV u16 f2bf(float f) {
    unsigned u = __float_as_uint(f);
    return (u16)((u + 0x7fffu + ((u >> 16) & 1u)) >> 16);  // RNE
}
DEV void unpack2(unsigned u, float& a, float& b) {
    a = __uint_as_float(u << 16);
    b = __uint_as_float(u & 0xffff0000u);
}
DEV void unpack8u(uint4 u, float* f) {
    unpack2(u.x, f[0], f[1]); unpack2(u.y, f[2], f[3]);
    unpack2(u.z, f[4], f[5]); unpack2(u.w, f[6], f[7]);
}
DEV unsigned pack2f(float a, float b) { return (unsigned)f2bf(a) | ((unsigned)f2bf(b) << 16); }
DEV uint4 pack8f(const float* f) {
    uint4 u;
    u.x = pack2f(f[0], f[1]); u.y = pack2f(f[2], f[3]);
    u.z = pack2f(f[4], f[5]); u.w = pack2f(f[6], f[7]);
    return u;
}
DEV float sigm(float x) { return 1.0f / (1.0f + __expf(-x)); }

// Problem constants
#define NAG 8
#define DM 256
#define NL 4
#define AD 12
#define TPB 4                 // tokens per block
#define MROWS 32
#define NBLK 4096

// ws (bf16 units) offsets: weights in MFMA B-frag order [ks][n][quad][j]
#define OFF_E1   0
#define OFF_E2   8192
#define OFF_QKVO 73728        // 16 matrices of 65536: (l*4+m), m: 0=q 1=k 2=v 3=o
#define OFF_TW2  1122304
#define OFF_ADW  1126400
#define WS_TOTAL 1128448
#define WS_BYTES (WS_TOTAL * 2)

// dynamic LDS layout (bytes), total 55040 -> 2 blocks/CU
#define L_R1    0         // 36864: trunk [256][72]u16 (th->to in place) | q[32][264]u16 | head x fp32 [32][264]
#define L_R1B   18432     //        k[32][264]u16 (second half of R1)
#define L_R2    36864     // 16896: state/nx/V [32][264]u16 ; bias tmp bf16 [4][4][8][64]
#define L_RED   53760     // 512:   fp32 [32][4] rms partials
#define L_SPOS  54272     // 256
#define L_SVEL  54528     // 256
#define L_ALV   54784     // 128
#define L_TEAM  54912     // 128
#define SMEM_BYTES 55040

enum { I_STATE=0, I_POS, I_VEL, I_TEAM, I_ALIVE, I_DEAD, I_EW1, I_EB1, I_EW2, I_EB2,
       I_TEMB, I_SEMB, I_TW1, I_TB1, I_TW2, I_TB2, I_ADW, I_ADB, I_NORMW,
       I_WQ, I_BQ, I_WK, I_BK, I_WV, I_BV, I_WO, I_BO, I_HW, I_HB, N_IN };

struct Args { const void* in[N_IN]; float* out; };

// ---------------- weight pre-conversion: fp32 [K][N] -> bf16 frag order ----------------
__global__ __launch_bounds__(256) void prep_kernel(Args a, u16* ws)
{
    int e = blockIdx.x * 256 + threadIdx.x;
    int mat = blockIdx.y;
    int size, offs, N, Kreal;
    const float* src;
    if (mat == 0)      { size = 8192;  offs = OFF_E1;  N = 256; Kreal = 16;  src = (const float*)a.in[I_EW1]; }
    else if (mat == 1) { size = 65536; offs = OFF_E2;  N = 256; Kreal = 256; src = (const float*)a.in[I_EW2]; }
    else if (mat < 18) {
        int q = mat - 2, l = q >> 2, m = q & 3;
        int wi = (m == 0) ? I_WQ : (m == 1) ? I_WK : (m == 2) ? I_WV : I_WO;
        size = 65536; offs = OFF_QKVO + q * 65536; N = 256; Kreal = 256;
        src = (const float*)a.in[wi] + l * 65536;
    }
    else if (mat == 18) { size = 4096; offs = OFF_TW2; N = 64; Kreal = 64; src = (const float*)a.in[I_TW2]; }
    else                { size = 2048; offs = OFF_ADW; N = 32; Kreal = 64; src = (const float*)a.in[I_ADW]; }
    if (e >= size) return;
    int ksblk = N * 32;
    int ks = e / ksblk, rem = e % ksblk;
    int n = rem >> 5, quad = (rem >> 3) & 3, j = rem & 7;
    int k = ks * 32 + quad * 8 + j;
    float v = 0.0f;
    if (k < Kreal) {
        if (mat == 19) v = src[((n >> 3) * 64 + k) * 8 + (n & 7)];   // adapt_W[l][k][h], n=l*8+h
        else           v = src[k * N + n];
    }
    ws[offs + e] = f2bf(v);
}

// ---------------- MFMA fragment loaders ----------------
DEV short8 ld_u4(const u16* p) {
    union { uint4 u; short8 s; } c;
    c.u = *(const uint4*)p;
    return c.s;
}
DEV short8 ld_afrag(const u16* A, int stride, int row0, int kofs, int l15, int quad) {
    return ld_u4(A + (row0 + l15) * stride + kofs + quad * 8);
}
DEV short8 ld_bws(const u16* w, int ksblk, int ks, int col, int l15, int quad) {
    return ld_u4(w + ks * ksblk + (col + l15) * 32 + quad * 8);
}
DEV short8 ld_bf32(const float* W, int N, int Kreal, int ks, int col, int l15, int quad) {
    short8 r;
    #pragma unroll
    for (int j = 0; j < 8; j++) {
        int k = ks * 32 + quad * 8 + j;
        float v = (k < Kreal) ? W[k * N + col + l15] : 0.0f;
        r[j] = (short)f2bf(v);
    }
    return r;
}

// M=32 GEMM: A [32][264] bf16 LDS, wave covers cols [colw, colw+64)
template<bool UW>
DEV void gemm32(const u16* A, const u16* wsW, const float* Wf,
                int Kb, int Kreal, int colw, int l15, int quad, floatx4 acc[2][4]) {
    for (int ks = 0; ks < Kb; ks++) {
        short8 af0 = ld_afrag(A, 264, 0,  ks * 32, l15, quad);
        short8 af1 = ld_afrag(A, 264, 16, ks * 32, l15, quad);
        short8 bf[4];
        #pragma unroll
        for (int nj = 0; nj < 4; nj++)
            bf[nj] = UW ? ld_bws(wsW, 8192, ks, colw + nj * 16, l15, quad)
                        : ld_bf32(Wf, 256, Kreal, ks, colw + nj * 16, l15, quad);
        #pragma unroll
        for (int nj = 0; nj < 4; nj++) {
            acc[0][nj] = __builtin_amdgcn_mfma_f32_16x16x32_bf16(af0, bf[nj], acc[0][nj], 0, 0, 0);
            acc[1][nj] = __builtin_amdgcn_mfma_f32_16x16x32_bf16(af1, bf[nj], acc[1][nj], 0, 0, 0);
        }
    }
}

template<bool UW>
__global__ __launch_bounds__(256, 2) void yemong_mfma(Args a, const u16* ws)
{
    extern __shared__ char smem[];
    u16* sR1   = (u16*)(smem + L_R1);     // trunk / q / head-x
    u16* sR1b  = (u16*)(smem + L_R1B);    // k
    u16* sR2   = (u16*)(smem + L_R2);     // state / nx / V / bias-tmp
    float* sred = (float*)(smem + L_RED);
    float* spos = (float*)(smem + L_SPOS);
    float* svel = (float*)(smem + L_SVEL);
    int* salive = (int*)(smem + L_ALV);
    int* steam  = (int*)(smem + L_TEAM);

    const int t = threadIdx.x;
    const int bid = blockIdx.x;
    const int lane = t & 63, wv = t >> 6;
    const int l15 = lane & 15, quad = lane >> 4;
    const int colw = wv * 64;

    // persistent registers
    float xr[2][4][4];        // residual x, C-layout: row=mi*16+quad*4+r, col=colw+nj*16+l15
    float bias_f[4][8];       // attn bias for this thread's (tok,h,i), [layer][j]
    const int tok = t >> 6, hh = (t >> 3) & 7, ii = t & 7;   // attention thread mapping

    // alive-layout probe (byte bools vs int32 bools), uniform
    unsigned mp = 0;
    const unsigned* au = (const unsigned*)a.in[I_ALIVE];
    #pragma unroll
    for (int i = 0; i < 16; i++) mp |= au[i];
    const bool abyte = (mp > 1u);
    auto aliveAt = [&](int r) -> int {
        int gi = bid * MROWS + r;
        return abyte ? (int)((const unsigned char*)a.in[I_ALIVE])[gi]
                     : ((const int*)a.in[I_ALIVE])[gi];
    };

    // -------- P0: metadata + masked state staging into R2 (k zero-padded to 32) --------
    if (t < MROWS) {
        salive[t] = aliveAt(t) ? 1 : 0;
        steam[t]  = ((const int*)a.in[I_TEAM])[bid * MROWS + t];
    }
    if (t >= 64 && t < 128) {
        int idx = t - 64, n = idx >> 1, d = idx & 1;
        spos[n * 2 + d] = ((const float*)a.in[I_POS])[(bid * MROWS + n) * 2 + d] * 1024.0f;
        svel[n * 2 + d] = ((const float*)a.in[I_VEL])[(bid * MROWS + n) * 2 + d];
    }
    {
        const float* gs = (const float*)a.in[I_STATE];
        const float* gd = (const float*)a.in[I_DEAD];
        #pragma unroll
        for (int it = 0; it < 4; it++) {
            int idx = t + 256 * it;              // 32 rows x 32 k
            int r = idx >> 5, kk = idx & 31;
            float v = 0.0f;
            if (kk < 16) v = aliveAt(r) ? gs[(bid * MROWS + r) * 16 + kk] : gd[kk];
            sR2[r * 264 + kk] = f2bf(v);
        }
    }
    __syncthreads();

    // -------- P1: enc1 (16->256) + silu, in place over R2 --------
    {
        floatx4 acc[2][4] = {};
        gemm32<UW>(sR2, ws + OFF_E1, (const float*)a.in[I_EW1], 1, 16, colw, l15, quad, acc);
        __syncthreads();
        const float* b1 = (const float*)a.in[I_EB1];
        #pragma unroll
        for (int nj = 0; nj < 4; nj++) {
            int c = colw + nj * 16 + l15;
            float bb = b1[c];
            #pragma unroll
            for (int mi = 0; mi < 2; mi++)
                #pragma unroll
                for (int r = 0; r < 4; r++) {
                    int row = mi * 16 + quad * 4 + r;
                    float v = acc[mi][nj][r] + bb;
                    sR2[row * 264 + c] = f2bf(v * sigm(v));
                }
        }
    }
    __syncthreads();

    // -------- P2: enc2 (256->256) + b2 + embeddings -> xr (registers) --------
    {
        floatx4 acc[2][4] = {};
        gemm32<UW>(sR2, ws + OFF_E2, (const float*)a.in[I_EW2], 8, 256, colw, l15, quad, acc);
        const float* b2 = (const float*)a.in[I_EB2];
        const float* te = (const float*)a.in[I_TEMB];
        const float* se = (const float*)a.in[I_SEMB];
        #pragma unroll
        for (int nj = 0; nj < 4; nj++) {
            int c = colw + nj * 16 + l15;
            float bb = b2[c];
            #pragma unroll
            for (int mi = 0; mi < 2; mi++)
                #pragma unroll
                for (int r = 0; r < 4; r++) {
                    int row = mi * 16 + quad * 4 + r;
                    xr[mi][nj][r] = acc[mi][nj][r] + bb + te[steam[row] * 256 + c] + se[(row & 7) * 256 + c];
                }
        }
    }
    __syncthreads();   // R2 reads done (bias tmp will reuse it)

    // -------- P3a: pair features + trunk1 (6->64) + silu -> R1 rows [256][72] --------
    {
        int ri = tok * 8 + ii, rj = tok * 8 + (t & 7);
        // pair (i,j): i=(t>>3)&7, j=t&7
        int pi = tok * 8 + ((t >> 3) & 7), pj = tok * 8 + (t & 7);
        float rx = spos[pi * 2 + 0] - spos[pj * 2 + 0];
        float ry = spos[pi * 2 + 1] - spos[pj * 2 + 1];
        rx -= rintf(rx * (1.0f / 1024.0f)) * 1024.0f;
        ry -= rintf(ry * (1.0f / 1024.0f)) * 1024.0f;
        float vx = svel[pi * 2 + 0] - svel[pj * 2 + 0];
        float vy = svel[pi * 2 + 1] - svel[pj * 2 + 1];
        float dn = sqrtf(rx * rx + ry * ry + 1e-8f) * (1.0f / 1024.0f);
        float f0 = rx * (1.0f / 1024.0f), f1 = ry * (1.0f / 1024.0f);
        float f4 = dn, f5 = 1.0f / (1.0f + dn);
        const float* W1 = (const float*)a.in[I_TW1];
        const float* B1 = (const float*)a.in[I_TB1];
        #pragma unroll
        for (int r = 0; r < 64; r += 2) {
            float v0 = B1[r], v1 = B1[r + 1];
            v0 = fmaf(f0, W1[r],       v0); v1 = fmaf(f0, W1[r + 1],       v1);
            v0 = fmaf(f1, W1[64 + r],  v0); v1 = fmaf(f1, W1[64 + r + 1],  v1);
            v0 = fmaf(vx, W1[128 + r], v0); v1 = fmaf(vx, W1[128 + r + 1], v1);
            v0 = fmaf(vy, W1[192 + r], v0); v1 = fmaf(vy, W1[192 + r + 1], v1);
            v0 = fmaf(f4, W1[256 + r], v0); v1 = fmaf(f4, W1[256 + r + 1], v1);
            v0 = fmaf(f5, W1[320 + r], v0); v1 = fmaf(f5, W1[320 + r + 1], v1);
            *(unsigned*)&sR1[t * 72 + r] = pack2f(v0 * sigm(v0), v1 * sigm(v1));
        }
        (void)ri; (void)rj;
    }
    __syncthreads();

    // -------- P3b: trunk2 (64->64) MFMA, in place over R1 (wave-local rows) --------
    {
        short8 taf[4][2];
        #pragma unroll
        for (int mi = 0; mi < 4; mi++)
            #pragma unroll
            for (int ks = 0; ks < 2; ks++)
                taf[mi][ks] = ld_afrag(sR1, 72, colw + mi * 16, ks * 32, l15, quad);
        floatx4 tacc[4][4] = {};
        #pragma unroll
        for (int ks = 0; ks < 2; ks++) {
            short8 bf[4];
            #pragma unroll
            for (int nj = 0; nj < 4; nj++)
                bf[nj] = UW ? ld_bws(ws + OFF_TW2, 2048, ks, nj * 16, l15, quad)
                            : ld_bf32((const float*)a.in[I_TW2], 64, 64, ks, nj * 16, l15, quad);
            #pragma unroll
            for (int mi = 0; mi < 4; mi++)
                #pragma unroll
                for (int nj = 0; nj < 4; nj++)
                    tacc[mi][nj] = __builtin_amdgcn_mfma_f32_16x16x32_bf16(taf[mi][ks], bf[nj], tacc[mi][nj], 0, 0, 0);
        }
        const float* B2 = (const float*)a.in[I_TB2];
        #pragma unroll
        for (int nj = 0; nj < 4; nj++) {
            int c = nj * 16 + l15;
            float bb = B2[c];
            #pragma unroll
            for (int mi = 0; mi < 4; mi++)
                #pragma unroll
                for (int r = 0; r < 4; r++) {
                    int row = colw + mi * 16 + quad * 4 + r;
                    sR1[row * 72 + c] = f2bf(tacc[mi][nj][r] + bb);
                }
        }
    }
    __syncthreads();

    // -------- P3c: adapt (64->32) -> bias tmp (R2, bf16) -> bias_f regs --------
    {
        floatx4 tacc[4][2] = {};
        #pragma unroll
        for (int ks = 0; ks < 2; ks++) {
            short8 bf[2];
            #pragma unroll
            for (int nj = 0; nj < 2; nj++) {
                if (UW) bf[nj] = ld_bws(ws + OFF_ADW, 1024, ks, nj * 16, l15, quad);
                else {
                    const float* adw = (const float*)a.in[I_ADW];
                    int n = nj * 16 + l15;
                    #pragma unroll
                    for (int j = 0; j < 8; j++) {
                        int k = ks * 32 + quad * 8 + j;
                        bf[nj][j] = (short)f2bf(k < 64 ? adw[((n >> 3) * 64 + k) * 8 + (n & 7)] : 0.0f);
                    }
                }
            }
            #pragma unroll
            for (int mi = 0; mi < 4; mi++) {
                short8 af = ld_afrag(sR1, 72, colw + mi * 16, ks * 32, l15, quad);
                #pragma unroll
                for (int nj = 0; nj < 2; nj++)
                    tacc[mi][nj] = __builtin_amdgcn_mfma_f32_16x16x32_bf16(af, bf[nj], tacc[mi][nj], 0, 0, 0);
            }
        }
        const float* adb = (const float*)a.in[I_ADB];
        #pragma unroll
        for (int nj = 0; nj < 2; nj++) {
            int n = nj * 16 + l15;
            float bb = adb[n];                      // [l][h] flat == n
            #pragma unroll
            for (int mi = 0; mi < 4; mi++)
                #pragma unroll
                for (int r = 0; r < 4; r++) {
                    int pl = mi * 16 + quad * 4 + r;   // pair within token (wave = token)
                    sR2[((wv * 4 + (n >> 3)) * 8 + (n & 7)) * 64 + pl] = f2bf(tacc[mi][nj][r] + bb);
                }
        }
        __syncthreads();
        #pragma unroll
        for (int l = 0; l < 4; l++) {
            uint4 u = *(const uint4*)&sR2[((tok * 4 + l) * 8 + hh) * 64 + ii * 8];
            unpack8u(u, bias_f[l]);
        }
    }

    // -------- P4: layers --------
    const float* normw = (const float*)a.in[I_NORMW];
    for (int l = 0; l < NL; l++) {
        // (a) rms: cross-wave partial reduce via RED
        float invr[8];
        {
            float ssv[8];
            #pragma unroll
            for (int mi = 0; mi < 2; mi++)
                #pragma unroll
                for (int r = 0; r < 4; r++) {
                    float s = 0.0f;
                    #pragma unroll
                    for (int nj = 0; nj < 4; nj++) { float v = xr[mi][nj][r]; s = fmaf(v, v, s); }
                    ssv[mi * 4 + r] = s;
                }
            #pragma unroll
            for (int m = 1; m < 16; m <<= 1)
                #pragma unroll
                for (int k2 = 0; k2 < 8; k2++) ssv[k2] += __shfl_xor(ssv[k2], m);
            if (l15 == 0) {
                #pragma unroll
                for (int mi = 0; mi < 2; mi++)
                    #pragma unroll
                    for (int r = 0; r < 4; r++)
                        sred[(mi * 16 + quad * 4 + r) * 4 + wv] = ssv[mi * 4 + r];
            }
            __syncthreads();
            #pragma unroll
            for (int mi = 0; mi < 2; mi++)
                #pragma unroll
                for (int r = 0; r < 4; r++) {
                    int row = mi * 16 + quad * 4 + r;
                    float s = sred[row * 4 + 0] + sred[row * 4 + 1] + sred[row * 4 + 2] + sred[row * 4 + 3];
                    invr[mi * 4 + r] = rsqrtf(s * (1.0f / 256.0f) + 1e-6f);
                }
        }
        // (b) nx -> R2 (bf16)
        {
            float nwv[4];
            #pragma unroll
            for (int nj = 0; nj < 4; nj++) nwv[nj] = normw[l * 256 + colw + nj * 16 + l15];
            #pragma unroll
            for (int nj = 0; nj < 4; nj++) {
                int c = colw + nj * 16 + l15;
                #pragma unroll
                for (int mi = 0; mi < 2; mi++)
                    #pragma unroll
                    for (int r = 0; r < 4; r++)
                        sR2[(mi * 16 + quad * 4 + r) * 264 + c] = f2bf(xr[mi][nj][r] * invr[mi * 4 + r] * nwv[nj]);
            }
        }
        __syncthreads();

        // (c) fused Q/K/V projections (3x ILP)
        {
            floatx4 acc[3][2][4] = {};
            const u16* wq = ws + OFF_QKVO + (l * 4 + 0) * 65536;
            const u16* wk = ws + OFF_QKVO + (l * 4 + 1) * 65536;
            const u16* wvv = ws + OFF_QKVO + (l * 4 + 2) * 65536;
            const float* fq = (const float*)a.in[I_WQ] + l * 65536;
            const float* fk = (const float*)a.in[I_WK] + l * 65536;
            const float* fv = (const float*)a.in[I_WV] + l * 65536;
            #pragma unroll 2
            for (int ks = 0; ks < 8; ks++) {
                short8 af0 = ld_afrag(sR2, 264, 0,  ks * 32, l15, quad);
                short8 af1 = ld_afrag(sR2, 264, 16, ks * 32, l15, quad);
                short8 bq[4], bk[4], bv[4];
                #pragma unroll
                for (int nj = 0; nj < 4; nj++) {
                    int c = colw + nj * 16;
                    bq[nj] = UW ? ld_bws(wq,  8192, ks, c, l15, quad) : ld_bf32(fq, 256, 256, ks, c, l15, quad);
                    bk[nj] = UW ? ld_bws(wk,  8192, ks, c, l15, quad) : ld_bf32(fk, 256, 256, ks, c, l15, quad);
                    bv[nj] = UW ? ld_bws(wvv, 8192, ks, c, l15, quad) : ld_bf32(fv, 256, 256, ks, c, l15, quad);
                }
                #pragma unroll
                for (int nj = 0; nj < 4; nj++) {
                    acc[0][0][nj] = __builtin_amdgcn_mfma_f32_16x16x32_bf16(af0, bq[nj], acc[0][0][nj], 0, 0, 0);
                    acc[0][1][nj] = __builtin_amdgcn_mfma_f32_16x16x32_bf16(af1, bq[nj], acc[0][1][nj], 0, 0, 0);
                    acc[1][0][nj] = __builtin_amdgcn_mfma_f32_16x16x32_bf16(af0, bk[nj], acc[1][0][nj], 0, 0, 0);
                    acc[1][1][nj] = __builtin_amdgcn_mfma_f32_16x16x32_bf16(af1, bk[nj], acc[1][1][nj], 0, 0, 0);
                    acc[2][0][nj] = __builtin_amdgcn_mfma_f32_16x16x32_bf16(af0, bv[nj], acc[2][0][nj], 0, 0, 0);
                    acc[2][1][nj] = __builtin_amdgcn_mfma_f32_16x16x32_bf16(af1, bv[nj], acc[2][1][nj], 0, 0, 0);
                }
            }
            // store q, k (R1/R1b)
            const float* bqf = (const float*)a.in[I_BQ] + l * 256;
            const float* bkf = (const float*)a.in[I_BK] + l * 256;
            #pragma unroll
            for (int nj = 0; nj < 4; nj++) {
                int c = colw + nj * 16 + l15;
                float b0 = bqf[c], b1 = bkf[c];
                #pragma unroll
                for (int mi = 0; mi < 2; mi++)
                    #pragma unroll
                    for (int r = 0; r < 4; r++) {
                        int row = mi * 16 + quad * 4 + r;
                        sR1 [row * 264 + c] = f2bf(acc[0][mi][nj][r] + b0);
                        sR1b[row * 264 + c] = f2bf(acc[1][mi][nj][r] + b1);
                    }
            }
            __syncthreads();    // all nx reads + q/k stores done
            // store V over R2
            const float* bvf = (const float*)a.in[I_BV] + l * 256;
            #pragma unroll
            for (int nj = 0; nj < 4; nj++) {
                int c = colw + nj * 16 + l15;
                float b2v = bvf[c];
                #pragma unroll
                for (int mi = 0; mi < 2; mi++)
                    #pragma unroll
                    for (int r = 0; r < 4; r++)
                        sR2[(mi * 16 + quad * 4 + r) * 264 + c] = f2bf(acc[2][mi][nj][r] + b2v);
            }
        }

        // (d) scores + softmax per thread (tok,h,i); q/k visible since pre-barrier
        float p[8];
        {
            int rq = tok * 8 + ii;
            float qv[32];
            #pragma unroll
            for (int g = 0; g < 4; g++) {
                uint4 u = *(const uint4*)&sR1[rq * 264 + hh * 32 + g * 8];
                unpack8u(u, &qv[g * 8]);
            }
            float sc[8];
            #pragma unroll
            for (int j = 0; j < 8; j++) {
                int rk = tok * 8 + j;
                float dot = 0.0f;
                #pragma unroll
                for (int g = 0; g < 4; g++) {
                    uint4 u = *(const uint4*)&sR1b[rk * 264 + hh * 32 + g * 8];
                    float kf[8];
                    unpack8u(u, kf);
                    #pragma unroll
                    for (int e2 = 0; e2 < 8; e2++) dot = fmaf(qv[g * 8 + e2], kf[e2], dot);
                }
                sc[j] = salive[tok * 8 + j] ? fmaf(dot, 0.17677669529663689f, bias_f[l][j]) : -1000000000.0f;
            }
            float mx = sc[0];
            #pragma unroll
            for (int j = 1; j < 8; j++) mx = fmaxf(mx, sc[j]);
            float s = 0.0f;
            #pragma unroll
            for (int j = 0; j < 8; j++) { p[j] = __expf(sc[j] - mx); s += p[j]; }
            float inv = 1.0f / s;
            #pragma unroll
            for (int j = 0; j < 8; j++) p[j] *= inv;
        }
        __syncthreads();   // V stores visible

        // (e) o = P @ V -> write over q (R1)
        {
            float o[32];
            #pragma unroll
            for (int cc = 0; cc < 32; cc++) o[cc] = 0.0f;
            #pragma unroll
            for (int j = 0; j < 8; j++) {
                float pj = p[j];
                int rv = tok * 8 + j;
                #pragma unroll
                for (int g = 0; g < 4; g++) {
                    uint4 u = *(const uint4*)&sR2[rv * 264 + hh * 32 + g * 8];
                    float vf[8];
                    unpack8u(u, vf);
                    #pragma unroll
                    for (int e2 = 0; e2 < 8; e2++) o[g * 8 + e2] = fmaf(pj, vf[e2], o[g * 8 + e2]);
                }
            }
            int rq = tok * 8 + ii;
            #pragma unroll
            for (int g = 0; g < 4; g++)
                *(uint4*)&sR1[rq * 264 + hh * 32 + g * 8] = pack8f(&o[g * 8]);
        }
        __syncthreads();

        // (f) x += o @ Wo + bo  (accumulate into registers)
        {
            floatx4 acc[2][4] = {};
            gemm32<UW>(sR1, ws + OFF_QKVO + (l * 4 + 3) * 65536, (const float*)a.in[I_WO] + l * 65536,
                       8, 256, colw, l15, quad, acc);
            const float* bo = (const float*)a.in[I_BO] + l * 256;
            #pragma unroll
            for (int nj = 0; nj < 4; nj++) {
                float bb = bo[colw + nj * 16 + l15];
                #pragma unroll
                for (int mi = 0; mi < 2; mi++)
                    #pragma unroll
                    for (int r = 0; r < 4; r++)
                        xr[mi][nj][r] += acc[mi][nj][r] + bb;
            }
        }
        __syncthreads();   // R1 (o) reads done before next layer's q stores / head staging
    }

    // -------- P5: stage x -> R1 (fp32) then head (256 -> 12) --------
    {
        float* xf = (float*)sR1;
        #pragma unroll
        for (int nj = 0; nj < 4; nj++) {
            int c = colw + nj * 16 + l15;
            #pragma unroll
            for (int mi = 0; mi < 2; mi++)
                #pragma unroll
                for (int r = 0; r < 4; r++)
                    xf[(mi * 16 + quad * 4 + r) * 264 + c] = xr[mi][nj][r];
        }
        __syncthreads();
        int row = t >> 3, pp = t & 7;
        const float* HW = (const float*)a.in[I_HW];
        float ah[12];
        #pragma unroll
        for (int c = 0; c < 12; c++) ah[c] = 0.0f;
        for (int kk = pp * 32; kk < pp * 32 + 32; kk++) {
            float xv = xf[row * 264 + kk];
            #pragma unroll
            for (int c = 0; c < 12; c++) ah[c] = fmaf(xv, HW[kk * 12 + c], ah[c]);
        }
        #pragma unroll
        for (int c = 0; c < 12; c++) {
            ah[c] += __shfl_xor(ah[c], 1);
            ah[c] += __shfl_xor(ah[c], 2);
            ah[c] += __shfl_xor(ah[c], 4);
        }
        if (pp == 0) {
            const float* hb = (const float*)a.in[I_HB];
            #pragma unroll
            for (int c = 0; c < 12; c++)
                a.out[(bid * MROWS + row) * AD + c] = ah[c] + hb[c];
        }
    }
}

extern "C" void kernel_launch(void* const* d_in, const int* in_sizes, int n_in,
                              void* d_out, int out_size, void* d_ws, size_t ws_size,
                              hipStream_t stream) {
    (void)in_sizes; (void)n_in; (void)out_size;
    Args a;
    for (int i = 0; i < N_IN; i++) a.in[i] = d_in[i];
    a.out = (float*)d_out;
    u16* ws16 = (u16*)d_ws;
    const bool use_ws = (ws_size >= (size_t)WS_BYTES) && (d_ws != nullptr);
    if (use_ws) {
        hipLaunchKernelGGL(prep_kernel, dim3(256, 20), dim3(256), 0, stream, a, ws16);
        hipFuncSetAttribute((const void*)yemong_mfma<true>, hipFuncAttributeMaxDynamicSharedMemorySize, SMEM_BYTES);
        hipLaunchKernelGGL((yemong_mfma<true>), dim3(NBLK), dim3(256), SMEM_BYTES, stream, a, ws16);
    } else {
        hipFuncSetAttribute((const void*)yemong_mfma<false>, hipFuncAttributeMaxDynamicSharedMemorySize, SMEM_BYTES);
        hipLaunchKernelGGL((yemong_mfma<false>), dim3(NBLK), dim3(256), SMEM_BYTES, stream, a, ws16);
    }
}